// Round 3
// baseline (81.828 us; speedup 1.0000x reference)
//
#include <hip/hip_runtime.h>

// out[b,h,w,o] = sum_{s1..s4} core[s1,s2,s3,s4,o] * a[s1]*b[s2]*c[s3]*d[s4]
// a = inp[b, h, w, :],   b = inp[b, h, w+1, :]
// c = inp[b, h+1, w, :], d = inp[b, h+1, w+1, :]
// input (1,128,128,128,2) fp32; core (2,2,2,2,4) fp32; out (128,127,127,4) fp32.
//
// R1: h-chunked blocks with register row-reuse (halves input fetch),
//     1-row software-pipelined prefetch, nontemporal output stores.
// R2: fix — __builtin_nontemporal_store needs a native vector type, not
//     HIP's float4 class; use clang ext_vector_type(4).

#define NB 128
#define NH 128
#define NW 128
#define HN 127
#define WN 127
#define CH 16   // output rows per block

typedef float float4v __attribute__((ext_vector_type(4)));

__global__ __launch_bounds__(128) void eps_kernel(const float* __restrict__ inp,
                                                  const float* __restrict__ core,
                                                  float* __restrict__ out) {
    __shared__ float cs[64];
    const int tid = threadIdx.x;
    if (tid < 64) cs[tid] = core[tid];
    __syncthreads();

    const int h0  = blockIdx.x * CH;              // first output row of chunk
    const int b   = blockIdx.y;
    const int hend = (h0 + CH < HN) ? (h0 + CH) : HN;
    const int w = tid;
    if (w >= WN) return;

    const float* base = inp + ((size_t)(b * NH) * NW + w) * 2;  // row 0 of this (b, w)
    const size_t rstride = (size_t)NW * 2;

    // cur = row h, nxt = row h+1 (each: own float2 + neighbor float2)
    float2 cur_a = *(const float2*)(base + (size_t)h0 * rstride);
    float2 cur_b = *(const float2*)(base + (size_t)h0 * rstride + 2);
    float2 nxt_a = *(const float2*)(base + (size_t)(h0 + 1) * rstride);
    float2 nxt_b = *(const float2*)(base + (size_t)(h0 + 1) * rstride + 2);

    for (int h = h0; h < hend; ++h) {
        // prefetch row h+2 (clamped; rows 0..127 are all valid)
        int hp = h + 2; if (hp > NH - 1) hp = NH - 1;
        float2 pf_a = *(const float2*)(base + (size_t)hp * rstride);
        float2 pf_b = *(const float2*)(base + (size_t)hp * rstride + 2);

        // ab from top row (cur), cd from bottom row (nxt)
        float ab[4] = {cur_a.x * cur_b.x, cur_a.x * cur_b.y,
                       cur_a.y * cur_b.x, cur_a.y * cur_b.y};
        float cd[4] = {nxt_a.x * nxt_b.x, nxt_a.x * nxt_b.y,
                       nxt_a.y * nxt_b.x, nxt_a.y * nxt_b.y};

        float4v acc = (float4v)(0.f);
        #pragma unroll
        for (int i = 0; i < 4; ++i) {
            #pragma unroll
            for (int j = 0; j < 4; ++j) {
                const float wt = ab[i] * cd[j];
                const float* cr = &cs[(i * 4 + j) * 4];
                acc.x += wt * cr[0];
                acc.y += wt * cr[1];
                acc.z += wt * cr[2];
                acc.w += wt * cr[3];
            }
        }

        float4v* dst = (float4v*)(out + ((size_t)(b * HN + h) * WN + w) * 4);
        __builtin_nontemporal_store(acc, dst);

        cur_a = nxt_a; cur_b = nxt_b;
        nxt_a = pf_a;  nxt_b = pf_b;
    }
}

extern "C" void kernel_launch(void* const* d_in, const int* in_sizes, int n_in,
                              void* d_out, int out_size, void* d_ws, size_t ws_size,
                              hipStream_t stream) {
    const float* inp  = (const float*)d_in[0];
    const float* core = (const float*)d_in[1];
    float* out = (float*)d_out;
    dim3 grid((HN + CH - 1) / CH, NB);  // (8, 128)
    eps_kernel<<<grid, 128, 0, stream>>>(inp, core, out);
}

// Round 4
// 77.564 us; speedup vs baseline: 1.0550x; 1.0550x over previous
//
#include <hip/hip_runtime.h>

// out[b,h,w,o] = sum_{s1..s4} core[s1,s2,s3,s4,o] * a[s1]*b[s2]*c[s3]*d[s4]
// a = inp[b, h, w, :],   b = inp[b, h, w+1, :]
// c = inp[b, h+1, w, :], d = inp[b, h+1, w+1, :]
// input (1,128,128,128,2) fp32; core (2,2,2,2,4) fp32; out (128,127,127,4) fp32.
//
// R3: CH=4 chunks — 4096 blocks (full occupancy: 16 blk/CU x 2 waves) with all
//     10 row-loads issued independently up front (max MLP), register h-reuse
//     (fetch = 5/4 x 16 MB), nontemporal float4 output stores.

#define NB 128
#define NH 128
#define NW 128
#define HN 127
#define WN 127
#define CH 4    // output rows per block

typedef float float4v __attribute__((ext_vector_type(4)));

__global__ __launch_bounds__(128) void eps_kernel(const float* __restrict__ inp,
                                                  const float* __restrict__ core,
                                                  float* __restrict__ out) {
    __shared__ float cs[64];
    const int tid = threadIdx.x;
    if (tid < 64) cs[tid] = core[tid];
    __syncthreads();

    const int h0 = blockIdx.x * CH;   // first output row of chunk
    const int b  = blockIdx.y;
    const int w  = tid;
    if (w >= WN) return;

    const float* base = inp + ((size_t)(b * NH) * NW + w) * 2;
    const size_t rstride = (size_t)NW * 2;

    // Load rows h0 .. h0+CH (CH+1 rows), each: own float2 + right-neighbor float2.
    // All loads independent -> issued back-to-back, full MLP.
    float2 rA[CH + 1], rB[CH + 1];
    #pragma unroll
    for (int r = 0; r <= CH; ++r) {
        int hr = h0 + r;
        if (hr > NH - 1) hr = NH - 1;          // clamp (last chunk only; harmless re-read)
        const float* p = base + (size_t)hr * rstride;
        rA[r] = *(const float2*)p;
        rB[r] = *(const float2*)(p + 2);
    }

    #pragma unroll
    for (int r = 0; r < CH; ++r) {
        const int h = h0 + r;
        if (h >= HN) break;                    // only trims last chunk (h0=124)

        float ab[4] = {rA[r].x * rB[r].x, rA[r].x * rB[r].y,
                       rA[r].y * rB[r].x, rA[r].y * rB[r].y};
        float cd[4] = {rA[r + 1].x * rB[r + 1].x, rA[r + 1].x * rB[r + 1].y,
                       rA[r + 1].y * rB[r + 1].x, rA[r + 1].y * rB[r + 1].y};

        float4v acc = (float4v)(0.f);
        #pragma unroll
        for (int i = 0; i < 4; ++i) {
            #pragma unroll
            for (int j = 0; j < 4; ++j) {
                const float wt = ab[i] * cd[j];
                const float* cr = &cs[(i * 4 + j) * 4];
                acc.x += wt * cr[0];
                acc.y += wt * cr[1];
                acc.z += wt * cr[2];
                acc.w += wt * cr[3];
            }
        }

        float4v* dst = (float4v*)(out + ((size_t)(b * HN + h) * WN + w) * 4);
        __builtin_nontemporal_store(acc, dst);
    }
}

extern "C" void kernel_launch(void* const* d_in, const int* in_sizes, int n_in,
                              void* d_out, int out_size, void* d_ws, size_t ws_size,
                              hipStream_t stream) {
    const float* inp  = (const float*)d_in[0];
    const float* core = (const float*)d_in[1];
    float* out = (float*)d_out;
    dim3 grid((HN + CH - 1) / CH, NB);  // (32, 128)
    eps_kernel<<<grid, 128, 0, stream>>>(inp, core, out);
}

// Round 5
// 77.447 us; speedup vs baseline: 1.0566x; 1.0015x over previous
//
#include <hip/hip_runtime.h>

// out[b,h,w,o] = sum_{s1..s4} core[s1,s2,s3,s4,o] * a[s1]*b[s2]*c[s3]*d[s4]
// a = inp[b, h, w, :],   b = inp[b, h, w+1, :]
// c = inp[b, h+1, w, :], d = inp[b, h+1, w+1, :]
// input (1,128,128,128,2) fp32; core (2,2,2,2,4) fp32; out (128,127,127,4) fp32.
//
// R4: CH=8 chunks — fetch = 9/8 x 16 MB = 18 MB. 2048 blocks -> 16 waves/CU;
//     all 18 row-loads issued independently up front (9.2 KB in flight/wave,
//     ~9 KB/CU suffices for 6 TB/s), register h-reuse, NT float4 stores.

#define NB 128
#define NH 128
#define NW 128
#define HN 127
#define WN 127
#define CH 8    // output rows per block

typedef float float4v __attribute__((ext_vector_type(4)));

__global__ __launch_bounds__(128) void eps_kernel(const float* __restrict__ inp,
                                                  const float* __restrict__ core,
                                                  float* __restrict__ out) {
    __shared__ float cs[64];
    const int tid = threadIdx.x;
    if (tid < 64) cs[tid] = core[tid];
    __syncthreads();

    const int h0 = blockIdx.x * CH;   // first output row of chunk
    const int b  = blockIdx.y;
    const int w  = tid;
    if (w >= WN) return;

    const float* base = inp + ((size_t)(b * NH) * NW + w) * 2;
    const size_t rstride = (size_t)NW * 2;

    // Load rows h0 .. h0+CH (CH+1 rows), each: own float2 + right-neighbor
    // float2. All loads independent -> issued back-to-back, full MLP.
    float2 rA[CH + 1], rB[CH + 1];
    #pragma unroll
    for (int r = 0; r <= CH; ++r) {
        int hr = h0 + r;
        if (hr > NH - 1) hr = NH - 1;          // clamp (last chunk only)
        const float* p = base + (size_t)hr * rstride;
        rA[r] = *(const float2*)p;
        rB[r] = *(const float2*)(p + 2);
    }

    #pragma unroll
    for (int r = 0; r < CH; ++r) {
        const int h = h0 + r;
        if (h >= HN) break;                    // trims last chunk (h0=120: 7 rows)

        float ab[4] = {rA[r].x * rB[r].x, rA[r].x * rB[r].y,
                       rA[r].y * rB[r].x, rA[r].y * rB[r].y};
        float cd[4] = {rA[r + 1].x * rB[r + 1].x, rA[r + 1].x * rB[r + 1].y,
                       rA[r + 1].y * rB[r + 1].x, rA[r + 1].y * rB[r + 1].y};

        float4v acc = (float4v)(0.f);
        #pragma unroll
        for (int i = 0; i < 4; ++i) {
            #pragma unroll
            for (int j = 0; j < 4; ++j) {
                const float wt = ab[i] * cd[j];
                const float* cr = &cs[(i * 4 + j) * 4];
                acc.x += wt * cr[0];
                acc.y += wt * cr[1];
                acc.z += wt * cr[2];
                acc.w += wt * cr[3];
            }
        }

        float4v* dst = (float4v*)(out + ((size_t)(b * HN + h) * WN + w) * 4);
        __builtin_nontemporal_store(acc, dst);
    }
}

extern "C" void kernel_launch(void* const* d_in, const int* in_sizes, int n_in,
                              void* d_out, int out_size, void* d_ws, size_t ws_size,
                              hipStream_t stream) {
    const float* inp  = (const float*)d_in[0];
    const float* core = (const float*)d_in[1];
    float* out = (float*)d_out;
    dim3 grid((HN + CH - 1) / CH, NB);  // (16, 128)
    eps_kernel<<<grid, 128, 0, stream>>>(inp, core, out);
}